// Round 7
// baseline (133.949 us; speedup 1.0000x reference)
//
#include <hip/hip_runtime.h>

// VectorQuantizer round 14: exact R8 structure (best measured: 99.9us total,
// main <=41us) + last-block-done finalize tail (normal stores — R11's
// regression was the nt-store/vmcnt-drain combo, not the tail itself).
// x [32,64,4096] f32, emb [512,64] f32. N = 131072 rows, D=64, K=512.
// prep: emb -> bf16 MFMA-fragment table (64KB) + ctab[k] = 4 - ||e_k||^2/2,
//       zero loss buckets + block counter.
// main: 512 blocks x 512 thr (8 waves). Block stages frag table + ctab into
//   LDS (linear, one barrier), each wave scans its 32 rows x all 512 cods from
//   LDS via mantissa-keyed fmax (low 10 mantissa bits = 1023-cod ->
//   argmax == first-min argmin). 67KB LDS -> 2 blocks/CU = 16 waves/CU.
//   Epilogue: q-store + fused loss; last block reduces buckets -> out[N*64].

#define VQ_OUTQ 8388608

typedef __attribute__((ext_vector_type(8))) short short8;
typedef __attribute__((ext_vector_type(4))) float f32x4;

__device__ __forceinline__ unsigned pk_bf16(float a, float b) {
    union { float f; unsigned u; } x, y; x.f = a; y.f = b;
    return ((y.u + 0x8000u) & 0xFFFF0000u) | ((x.u + 0x8000u) >> 16);
}

// ---- prep: fragment table + score-bias table + zero buckets/counter ------
__global__ __launch_bounds__(256) void vq_prep(
    const float* __restrict__ emb,
    short8* __restrict__ frag,      // 4096 slots x 16B
    float* __restrict__ ctab,       // 512: 4 - ||e_k||^2 / 2
    double* __restrict__ buck,      // 256
    int* __restrict__ cnt)          // 1
{
    const int s = blockIdx.x * 256 + threadIdx.x;   // 0..4095
    const int l = s & 63, kc = (s >> 6) & 1, ct = s >> 7;
    const int qs = l >> 4, ms = l & 15;
    const float* __restrict__ er = emb + (ct * 16 + ms) * 64 + kc * 32 + qs * 8;
    float4 p0 = *(const float4*)er;
    float4 p1 = *(const float4*)(er + 4);
    union { short8 s8; unsigned u[4]; } w;
    w.u[0] = pk_bf16(p0.x, p0.y); w.u[1] = pk_bf16(p0.z, p0.w);
    w.u[2] = pk_bf16(p1.x, p1.y); w.u[3] = pk_bf16(p1.z, p1.w);
    frag[s] = w.s8;

    if (s < 512) {
        const float4* __restrict__ e4 = (const float4*)emb + s * 16;
        float c = 0.f;
        #pragma unroll
        for (int i = 0; i < 16; ++i) {
            float4 e = e4[i];
            c = fmaf(e.x, e.x, c); c = fmaf(e.y, e.y, c);
            c = fmaf(e.z, e.z, c); c = fmaf(e.w, e.w, c);
        }
        ctab[s] = fmaf(-0.5f, c, 4.0f);
    }
    if (s < 256) buck[s] = 0.0;
    if (s == 0) *cnt = 0;
}

// ---- main ----------------------------------------------------------------
__global__ __launch_bounds__(512, 2) void vq_main(
    const float* __restrict__ x,
    const float* __restrict__ emb,
    const short8* __restrict__ frag,
    const float* __restrict__ ctab,
    float* __restrict__ qout,
    double* __restrict__ buck,
    int* __restrict__ cnt)
{
    __shared__ __align__(16) short8 sfrag[4096];   // 65536 B
    __shared__ float cks[512];                     // 2048 B
    __shared__ int idxs[8][32];                    // wave-private
    __shared__ int amlast;

    const int tid  = threadIdx.x;
    const int lane = tid & 63, wave = tid >> 6;
    const int m = lane & 15, quad = lane >> 4;

    const int rowbase = blockIdx.x * 256 + wave * 32;   // 32 rows/wave
    const int b = rowbase >> 12, t = rowbase & 4095;

    // ---- stage frag table + ctab into LDS (linear, conflict-free)
    #pragma unroll
    for (int i = 0; i < 8; ++i) {
        const int s = i * 512 + tid;
        sfrag[s] = frag[s];
    }
    cks[tid] = ctab[tid];                 // first 512 entries; 512 thr = exact
    __syncthreads();

    // ---- A-frags: x[b, d, t+row] direct global -> bf16
    short8 a[2][2];
    {
        const float* __restrict__ xa = x + (size_t)b * 262144 + t + m;
        #pragma unroll
        for (int rt = 0; rt < 2; ++rt) {
            #pragma unroll
            for (int kc = 0; kc < 2; ++kc) {
                const float* __restrict__ p =
                    xa + rt * 16 + (size_t)(kc * 32 + quad * 8) * 4096;
                float f[8];
                #pragma unroll
                for (int j = 0; j < 8; ++j) f[j] = p[(size_t)j * 4096];
                union { short8 s8; unsigned u[4]; } w;
                w.u[0] = pk_bf16(f[0], f[1]); w.u[1] = pk_bf16(f[2], f[3]);
                w.u[2] = pk_bf16(f[4], f[5]); w.u[3] = pk_bf16(f[6], f[7]);
                a[rt][kc] = w.s8;
            }
        }
    }

    // ---- scan all 512 cods from LDS: mantissa-keyed fmax
    float best[2][4];
    #pragma unroll
    for (int rt = 0; rt < 2; ++rt)
        #pragma unroll
        for (int r = 0; r < 4; ++r) best[rt][r] = 0.f;   // all real keys > 3

    #pragma unroll 4
    for (int ct = 0; ct < 32; ++ct) {
        short8 b0 = sfrag[ct * 128 + lane];
        short8 b1 = sfrag[ct * 128 + 64 + lane];
        const int cod = (ct << 4) + m;
        const float ck = cks[cod];
        const unsigned fk = 1023u - (unsigned)cod;
        #pragma unroll
        for (int rt = 0; rt < 2; ++rt) {
            f32x4 p = {0.f, 0.f, 0.f, 0.f};
            p = __builtin_amdgcn_mfma_f32_16x16x32_bf16(a[rt][0], b0, p, 0, 0, 0);
            p = __builtin_amdgcn_mfma_f32_16x16x32_bf16(a[rt][1], b1, p, 0, 0, 0);
            #pragma unroll
            for (int r = 0; r < 4; ++r) {
                float v = p[r] + ck;
                float k = __uint_as_float((__float_as_uint(v) & 0xFFFFFC00u) | fk);
                best[rt][r] = fmaxf(best[rt][r], k);
            }
        }
    }

    // ---- cross-m max-reduce; idx from winner's mantissa
    #pragma unroll
    for (int rt = 0; rt < 2; ++rt) {
        #pragma unroll
        for (int r = 0; r < 4; ++r) {
            float bv = best[rt][r];
            #pragma unroll
            for (int mm = 1; mm < 16; mm <<= 1)
                bv = fmaxf(bv, __shfl_xor(bv, mm, 64));
            if (m == 0)
                idxs[wave][rt * 16 + (quad << 2) + r] =
                    1023 - (int)(__float_as_uint(bv) & 1023u);
        }
    }
    // no barrier needed: idxs is wave-private, DS ops in-order per wave

    // ---- epilogue: wave's 32 rows = 8 KB contiguous; fused loss vs linear x
    {
        const f32x4* __restrict__ x4 = (const f32x4*)x + (size_t)rowbase * 16;
        f32x4* __restrict__ q4 = (f32x4*)qout + (size_t)rowbase * 16;
        const f32x4* __restrict__ e4 = (const f32x4*)emb;
        float ls = 0.f;
        #pragma unroll
        for (int j = 0; j < 8; ++j) {
            const int e = j * 64 + lane;       // float4 units, 0..511
            const int idx = idxs[wave][e >> 4];
            f32x4 q  = e4[idx * 16 + (e & 15)];
            f32x4 xr = x4[e];
            q4[e] = q;
            float dx = q.x - xr.x, dy = q.y - xr.y;
            float dz = q.z - xr.z, dw = q.w - xr.w;
            ls = fmaf(dx, dx, ls); ls = fmaf(dy, dy, ls);
            ls = fmaf(dz, dz, ls); ls = fmaf(dw, dw, ls);
        }
        #pragma unroll
        for (int off = 32; off > 0; off >>= 1)
            ls += __shfl_down(ls, off, 64);
        if (lane == 0)
            atomicAdd(&buck[(blockIdx.x * 8 + wave) & 255], (double)ls);
    }

    // ---- last-block-done finalize (replaces vq_finalize kernel)
    __syncthreads();
    if (tid == 0) {
        __threadfence();                       // order bucket adds before counter
        int p = __hip_atomic_fetch_add(cnt, 1, __ATOMIC_ACQ_REL,
                                       __HIP_MEMORY_SCOPE_AGENT);
        amlast = (p == (int)gridDim.x - 1);
    }
    __syncthreads();
    if (amlast && wave == 0) {
        double s = 0.0;
        #pragma unroll
        for (int i = 0; i < 4; ++i)
            s += __hip_atomic_load(&buck[i * 64 + lane], __ATOMIC_RELAXED,
                                   __HIP_MEMORY_SCOPE_AGENT);
        #pragma unroll
        for (int off = 32; off > 0; off >>= 1)
            s += __shfl_down(s, off, 64);
        if (lane == 0)
            qout[VQ_OUTQ] = (float)(1.25 * s / 8388608.0);
    }
}

extern "C" void kernel_launch(void* const* d_in, const int* in_sizes, int n_in,
                              void* d_out, int out_size, void* d_ws, size_t ws_size,
                              hipStream_t stream)
{
    const float* x   = (const float*)d_in[0];
    const float* emb = (const float*)d_in[1];
    float* out = (float*)d_out;

    short8* frag = (short8*)d_ws;                          // 65536 B
    float*  ctab = (float*)((char*)d_ws + 65536);          // 2048 B
    double* buck = (double*)((char*)d_ws + 65536 + 2048);  // 2048 B
    int*    cnt  = (int*)((char*)d_ws + 65536 + 2048 + 2048);

    vq_prep<<<dim3(16), dim3(256), 0, stream>>>(emb, frag, ctab, buck, cnt);
    vq_main<<<dim3(512), dim3(512), 0, stream>>>(x, emb, frag, ctab, out, buck, cnt);
}

// Round 8
// 103.829 us; speedup vs baseline: 1.2901x; 1.2901x over previous
//
#include <hip/hip_runtime.h>

// VectorQuantizer round 15: two-pass LDS scan for 4 blocks/CU.
// R14 lesson: finalize tail = +20us (post-store vmcnt drain) -> separate
// finalize kernel restored. R8 lesson: LDS staging itself is cheap (32MB L2
// chip-wide) but 67KB LDS caps 2 blocks/CU = one generation, all latency
// exposed. Fix: stage half the table (32KB) at a time, scan cods 0-255 then
// restage+scan 256-511. LDS ~35KB -> 4 blocks/CU = 32 waves/CU. Grid 1024x512,
// 16 rows/wave; chip-wide staging bytes unchanged. Bit-identical results
// (mantissa keys are unique -> fmax order-independent).
// x [32,64,4096] f32, emb [512,64] f32. N = 131072 rows, D=64, K=512.
// out[0..N*64) = emb[argmin][:] fp32 exact; out[N*64] = 1.25*mean((q-x_lin)^2).

#define VQ_OUTQ 8388608

typedef __attribute__((ext_vector_type(8))) short short8;
typedef __attribute__((ext_vector_type(4))) float f32x4;

__device__ __forceinline__ unsigned pk_bf16(float a, float b) {
    union { float f; unsigned u; } x, y; x.f = a; y.f = b;
    return ((y.u + 0x8000u) & 0xFFFF0000u) | ((x.u + 0x8000u) >> 16);
}

// ---- prep: fragment table + score-bias table + zero loss buckets ---------
__global__ __launch_bounds__(256) void vq_prep(
    const float* __restrict__ emb,
    short8* __restrict__ frag,      // 4096 slots x 16B
    float* __restrict__ ctab,       // 512: 4 - ||e_k||^2 / 2
    double* __restrict__ buck)      // 256
{
    const int s = blockIdx.x * 256 + threadIdx.x;   // 0..4095
    const int l = s & 63, kc = (s >> 6) & 1, ct = s >> 7;
    const int qs = l >> 4, ms = l & 15;
    const float* __restrict__ er = emb + (ct * 16 + ms) * 64 + kc * 32 + qs * 8;
    float4 p0 = *(const float4*)er;
    float4 p1 = *(const float4*)(er + 4);
    union { short8 s8; unsigned u[4]; } w;
    w.u[0] = pk_bf16(p0.x, p0.y); w.u[1] = pk_bf16(p0.z, p0.w);
    w.u[2] = pk_bf16(p1.x, p1.y); w.u[3] = pk_bf16(p1.z, p1.w);
    frag[s] = w.s8;

    if (s < 512) {
        const float4* __restrict__ e4 = (const float4*)emb + s * 16;
        float c = 0.f;
        #pragma unroll
        for (int i = 0; i < 16; ++i) {
            float4 e = e4[i];
            c = fmaf(e.x, e.x, c); c = fmaf(e.y, e.y, c);
            c = fmaf(e.z, e.z, c); c = fmaf(e.w, e.w, c);
        }
        ctab[s] = fmaf(-0.5f, c, 4.0f);
    }
    if (s < 256) buck[s] = 0.0;
}

// ---- main ----------------------------------------------------------------
__global__ __launch_bounds__(512, 4) void vq_main(
    const float* __restrict__ x,
    const float* __restrict__ emb,
    const short8* __restrict__ frag,
    const float* __restrict__ ctab,
    float* __restrict__ qout,
    double* __restrict__ buck)
{
    __shared__ __align__(16) short8 sfrag[2048];   // 32768 B (half table)
    __shared__ float cks[512];                     // 2048 B
    __shared__ int idxs[8][16];                    // wave-private

    const int tid  = threadIdx.x;
    const int lane = tid & 63, wave = tid >> 6;
    const int m = lane & 15, quad = lane >> 4;

    const int rowbase = blockIdx.x * 128 + wave * 16;   // 16 rows/wave
    const int b = rowbase >> 12, t = rowbase & 4095;

    // ---- A-frags: x[b, d, t+row] -> bf16. Issued before staging so HBM
    //      latency overlaps the L2->LDS copy.
    short8 a[2];
    {
        const float* __restrict__ xa = x + (size_t)b * 262144 + t + m;
        #pragma unroll
        for (int kc = 0; kc < 2; ++kc) {
            const float* __restrict__ p = xa + (size_t)(kc * 32 + quad * 8) * 4096;
            float f[8];
            #pragma unroll
            for (int j = 0; j < 8; ++j) f[j] = p[(size_t)j * 4096];
            union { short8 s8; unsigned u[4]; } w;
            w.u[0] = pk_bf16(f[0], f[1]); w.u[1] = pk_bf16(f[2], f[3]);
            w.u[2] = pk_bf16(f[4], f[5]); w.u[3] = pk_bf16(f[6], f[7]);
            a[kc] = w.s8;
        }
    }

    // ---- stage pass 0: cods 0..255 (32 KB) + full ctab
    #pragma unroll
    for (int i = 0; i < 4; ++i)
        sfrag[i * 512 + tid] = frag[i * 512 + tid];
    cks[tid] = ctab[tid];
    __syncthreads();

    float best[4];
    #pragma unroll
    for (int r = 0; r < 4; ++r) best[r] = 0.f;      // all real keys > 3

    #pragma unroll 4
    for (int ct = 0; ct < 16; ++ct) {
        short8 b0 = sfrag[ct * 128 + lane];
        short8 b1 = sfrag[ct * 128 + 64 + lane];
        const int cod = (ct << 4) + m;
        const float ck = cks[cod];
        const unsigned fk = 1023u - (unsigned)cod;
        f32x4 p = {0.f, 0.f, 0.f, 0.f};
        p = __builtin_amdgcn_mfma_f32_16x16x32_bf16(a[0], b0, p, 0, 0, 0);
        p = __builtin_amdgcn_mfma_f32_16x16x32_bf16(a[1], b1, p, 0, 0, 0);
        #pragma unroll
        for (int r = 0; r < 4; ++r) {
            float v = p[r] + ck;
            float k = __uint_as_float((__float_as_uint(v) & 0xFFFFFC00u) | fk);
            best[r] = fmaxf(best[r], k);
        }
    }

    // ---- stage pass 1: cods 256..511 into the same buffer
    __syncthreads();                               // all waves done reading buf
    #pragma unroll
    for (int i = 0; i < 4; ++i)
        sfrag[i * 512 + tid] = frag[2048 + i * 512 + tid];
    __syncthreads();

    #pragma unroll 4
    for (int ct = 16; ct < 32; ++ct) {
        short8 b0 = sfrag[(ct - 16) * 128 + lane];
        short8 b1 = sfrag[(ct - 16) * 128 + 64 + lane];
        const int cod = (ct << 4) + m;
        const float ck = cks[cod];
        const unsigned fk = 1023u - (unsigned)cod;
        f32x4 p = {0.f, 0.f, 0.f, 0.f};
        p = __builtin_amdgcn_mfma_f32_16x16x32_bf16(a[0], b0, p, 0, 0, 0);
        p = __builtin_amdgcn_mfma_f32_16x16x32_bf16(a[1], b1, p, 0, 0, 0);
        #pragma unroll
        for (int r = 0; r < 4; ++r) {
            float v = p[r] + ck;
            float k = __uint_as_float((__float_as_uint(v) & 0xFFFFFC00u) | fk);
            best[r] = fmaxf(best[r], k);
        }
    }

    // ---- cross-m max-reduce; idx from winner's mantissa
    #pragma unroll
    for (int r = 0; r < 4; ++r) {
        float bv = best[r];
        #pragma unroll
        for (int mm = 1; mm < 16; mm <<= 1)
            bv = fmaxf(bv, __shfl_xor(bv, mm, 64));
        if (m == 0)
            idxs[wave][(quad << 2) + r] =
                1023 - (int)(__float_as_uint(bv) & 1023u);
    }
    // no barrier needed: idxs is wave-private, DS ops in-order per wave

    // ---- epilogue: wave's 16 rows = 4 KB contiguous; fused loss vs linear x
    {
        const f32x4* __restrict__ x4 = (const f32x4*)x + (size_t)rowbase * 16;
        f32x4* __restrict__ q4 = (f32x4*)qout + (size_t)rowbase * 16;
        const f32x4* __restrict__ e4 = (const f32x4*)emb;
        float ls = 0.f;
        #pragma unroll
        for (int j = 0; j < 4; ++j) {
            const int e = j * 64 + lane;       // float4 units, 0..255
            const int idx = idxs[wave][e >> 4];
            f32x4 q  = e4[idx * 16 + (e & 15)];
            f32x4 xr = x4[e];
            q4[e] = q;
            float dx = q.x - xr.x, dy = q.y - xr.y;
            float dz = q.z - xr.z, dw = q.w - xr.w;
            ls = fmaf(dx, dx, ls); ls = fmaf(dy, dy, ls);
            ls = fmaf(dz, dz, ls); ls = fmaf(dw, dw, ls);
        }
        #pragma unroll
        for (int off = 32; off > 0; off >>= 1)
            ls += __shfl_down(ls, off, 64);
        if (lane == 0)
            atomicAdd(&buck[(blockIdx.x * 8 + wave) & 255], (double)ls);
    }
}

// ---- finalize ------------------------------------------------------------
__global__ void vq_finalize(const double* __restrict__ buck,
                            float* __restrict__ out)
{
    const int lane = threadIdx.x & 63;
    double s = buck[lane] + buck[64 + lane] + buck[128 + lane] + buck[192 + lane];
    #pragma unroll
    for (int off = 32; off > 0; off >>= 1)
        s += __shfl_down(s, off, 64);
    if (lane == 0)
        out[VQ_OUTQ] = (float)(1.25 * s / 8388608.0);
}

extern "C" void kernel_launch(void* const* d_in, const int* in_sizes, int n_in,
                              void* d_out, int out_size, void* d_ws, size_t ws_size,
                              hipStream_t stream)
{
    const float* x   = (const float*)d_in[0];
    const float* emb = (const float*)d_in[1];
    float* out = (float*)d_out;

    short8* frag = (short8*)d_ws;                          // 65536 B
    float*  ctab = (float*)((char*)d_ws + 65536);          // 2048 B
    double* buck = (double*)((char*)d_ws + 65536 + 2048);  // 2048 B

    vq_prep<<<dim3(16), dim3(256), 0, stream>>>(emb, frag, ctab, buck);
    vq_main<<<dim3(1024), dim3(512), 0, stream>>>(x, emb, frag, ctab, out, buck);
    vq_finalize<<<dim3(1), dim3(64), 0, stream>>>(buck, out);
}

// Round 9
// 99.404 us; speedup vs baseline: 1.3475x; 1.0445x over previous
//
#include <hip/hip_runtime.h>

// VectorQuantizer round 16: R8 structure exactly (champion, 99.9us), with two
// in-structure deltas: (1) staging via __builtin_amdgcn_global_load_lds w=16
// (no VGPR round-trip, compiler never auto-emits); (2) A-frag HBM loads issued
// before the L2->LDS staging so their latency hides under it.
// R11/R14 lesson (revised): per-block device-scope release => cross-XCD L2
// writeback storm (+20us) -> finalize stays a separate kernel.
// x [32,64,4096] f32, emb [512,64] f32. N = 131072 rows, D=64, K=512.
// prep: emb -> bf16 MFMA-fragment table (64KB) + ctab[k] = 4 - ||e_k||^2/2.
// main: 512 blocks x 512 thr (8 waves), 32 rows/wave, table in LDS, scan via
//   mantissa-keyed fmax (low 10 bits = 1023-cod -> argmax == first-min argmin).
// finalize: bucket reduce -> out[N*64] = 1.25*mean((q-x_lin)^2).

#define VQ_OUTQ 8388608

typedef __attribute__((ext_vector_type(8))) short short8;
typedef __attribute__((ext_vector_type(4))) float f32x4;

__device__ __forceinline__ unsigned pk_bf16(float a, float b) {
    union { float f; unsigned u; } x, y; x.f = a; y.f = b;
    return ((y.u + 0x8000u) & 0xFFFF0000u) | ((x.u + 0x8000u) >> 16);
}

__device__ __forceinline__ void gl_lds16(const void* g, void* l) {
    __builtin_amdgcn_global_load_lds(
        (const __attribute__((address_space(1))) void*)g,
        (__attribute__((address_space(3))) void*)l, 16, 0, 0);
}

__device__ __forceinline__ void gl_lds4(const void* g, void* l) {
    __builtin_amdgcn_global_load_lds(
        (const __attribute__((address_space(1))) void*)g,
        (__attribute__((address_space(3))) void*)l, 4, 0, 0);
}

// ---- prep: fragment table + score-bias table + zero loss buckets ---------
__global__ __launch_bounds__(256) void vq_prep(
    const float* __restrict__ emb,
    short8* __restrict__ frag,      // 4096 slots x 16B
    float* __restrict__ ctab,       // 512: 4 - ||e_k||^2 / 2
    double* __restrict__ buck)      // 256
{
    const int s = blockIdx.x * 256 + threadIdx.x;   // 0..4095
    const int l = s & 63, kc = (s >> 6) & 1, ct = s >> 7;
    const int qs = l >> 4, ms = l & 15;
    const float* __restrict__ er = emb + (ct * 16 + ms) * 64 + kc * 32 + qs * 8;
    float4 p0 = *(const float4*)er;
    float4 p1 = *(const float4*)(er + 4);
    union { short8 s8; unsigned u[4]; } w;
    w.u[0] = pk_bf16(p0.x, p0.y); w.u[1] = pk_bf16(p0.z, p0.w);
    w.u[2] = pk_bf16(p1.x, p1.y); w.u[3] = pk_bf16(p1.z, p1.w);
    frag[s] = w.s8;

    if (s < 512) {
        const float4* __restrict__ e4 = (const float4*)emb + s * 16;
        float c = 0.f;
        #pragma unroll
        for (int i = 0; i < 16; ++i) {
            float4 e = e4[i];
            c = fmaf(e.x, e.x, c); c = fmaf(e.y, e.y, c);
            c = fmaf(e.z, e.z, c); c = fmaf(e.w, e.w, c);
        }
        ctab[s] = fmaf(-0.5f, c, 4.0f);
    }
    if (s < 256) buck[s] = 0.0;
}

// ---- main ----------------------------------------------------------------
__global__ __launch_bounds__(512, 2) void vq_main(
    const float* __restrict__ x,
    const float* __restrict__ emb,
    const short8* __restrict__ frag,
    const float* __restrict__ ctab,
    float* __restrict__ qout,
    double* __restrict__ buck)
{
    __shared__ __align__(16) short8 sfrag[4096];   // 65536 B
    __shared__ float cks[512];                     // 2048 B
    __shared__ int idxs[8][32];                    // wave-private

    const int tid  = threadIdx.x;
    const int lane = tid & 63, wave = tid >> 6;
    const int m = lane & 15, quad = lane >> 4;

    const int rowbase = blockIdx.x * 256 + wave * 32;   // 32 rows/wave
    const int b = rowbase >> 12, t = rowbase & 4095;

    // ---- A-frags first: x[b, d, t+row] -> bf16 (HBM; latency hides under
    //      the L2->LDS staging issued below)
    short8 a[2][2];
    {
        const float* __restrict__ xa = x + (size_t)b * 262144 + t + m;
        #pragma unroll
        for (int rt = 0; rt < 2; ++rt) {
            #pragma unroll
            for (int kc = 0; kc < 2; ++kc) {
                const float* __restrict__ p =
                    xa + rt * 16 + (size_t)(kc * 32 + quad * 8) * 4096;
                float f[8];
                #pragma unroll
                for (int j = 0; j < 8; ++j) f[j] = p[(size_t)j * 4096];
                union { short8 s8; unsigned u[4]; } w;
                w.u[0] = pk_bf16(f[0], f[1]); w.u[1] = pk_bf16(f[2], f[3]);
                w.u[2] = pk_bf16(f[4], f[5]); w.u[3] = pk_bf16(f[6], f[7]);
                a[rt][kc] = w.s8;
            }
        }
    }

    // ---- stage frag table + ctab into LDS via global_load_lds (direct,
    //      no VGPR round-trip; dest = wave-uniform base + lane*16, linear)
    #pragma unroll
    for (int i = 0; i < 8; ++i) {
        const int s = i * 512 + tid;
        gl_lds16(&frag[s], &sfrag[i * 512 + wave * 64]);
    }
    gl_lds4(&ctab[tid], &cks[wave * 64]);
    __syncthreads();

    // ---- scan all 512 cods from LDS: mantissa-keyed fmax
    float best[2][4];
    #pragma unroll
    for (int rt = 0; rt < 2; ++rt)
        #pragma unroll
        for (int r = 0; r < 4; ++r) best[rt][r] = 0.f;   // all real keys > 3

    #pragma unroll 4
    for (int ct = 0; ct < 32; ++ct) {
        short8 b0 = sfrag[ct * 128 + lane];
        short8 b1 = sfrag[ct * 128 + 64 + lane];
        const int cod = (ct << 4) + m;
        const float ck = cks[cod];
        const unsigned fk = 1023u - (unsigned)cod;
        #pragma unroll
        for (int rt = 0; rt < 2; ++rt) {
            f32x4 p = {0.f, 0.f, 0.f, 0.f};
            p = __builtin_amdgcn_mfma_f32_16x16x32_bf16(a[rt][0], b0, p, 0, 0, 0);
            p = __builtin_amdgcn_mfma_f32_16x16x32_bf16(a[rt][1], b1, p, 0, 0, 0);
            #pragma unroll
            for (int r = 0; r < 4; ++r) {
                float v = p[r] + ck;
                float k = __uint_as_float((__float_as_uint(v) & 0xFFFFFC00u) | fk);
                best[rt][r] = fmaxf(best[rt][r], k);
            }
        }
    }

    // ---- cross-m max-reduce; idx from winner's mantissa
    #pragma unroll
    for (int rt = 0; rt < 2; ++rt) {
        #pragma unroll
        for (int r = 0; r < 4; ++r) {
            float bv = best[rt][r];
            #pragma unroll
            for (int mm = 1; mm < 16; mm <<= 1)
                bv = fmaxf(bv, __shfl_xor(bv, mm, 64));
            if (m == 0)
                idxs[wave][rt * 16 + (quad << 2) + r] =
                    1023 - (int)(__float_as_uint(bv) & 1023u);
        }
    }
    // no barrier needed: idxs is wave-private, DS ops in-order per wave

    // ---- epilogue: wave's 32 rows = 8 KB contiguous; fused loss vs linear x
    {
        const f32x4* __restrict__ x4 = (const f32x4*)x + (size_t)rowbase * 16;
        f32x4* __restrict__ q4 = (f32x4*)qout + (size_t)rowbase * 16;
        const f32x4* __restrict__ e4 = (const f32x4*)emb;
        float ls = 0.f;
        #pragma unroll
        for (int j = 0; j < 8; ++j) {
            const int e = j * 64 + lane;       // float4 units, 0..511
            const int idx = idxs[wave][e >> 4];
            f32x4 q  = e4[idx * 16 + (e & 15)];
            f32x4 xr = x4[e];
            q4[e] = q;
            float dx = q.x - xr.x, dy = q.y - xr.y;
            float dz = q.z - xr.z, dw = q.w - xr.w;
            ls = fmaf(dx, dx, ls); ls = fmaf(dy, dy, ls);
            ls = fmaf(dz, dz, ls); ls = fmaf(dw, dw, ls);
        }
        #pragma unroll
        for (int off = 32; off > 0; off >>= 1)
            ls += __shfl_down(ls, off, 64);
        if (lane == 0)
            atomicAdd(&buck[(blockIdx.x * 8 + wave) & 255], (double)ls);
    }
}

// ---- finalize ------------------------------------------------------------
__global__ void vq_finalize(const double* __restrict__ buck,
                            float* __restrict__ out)
{
    const int lane = threadIdx.x & 63;
    double s = buck[lane] + buck[64 + lane] + buck[128 + lane] + buck[192 + lane];
    #pragma unroll
    for (int off = 32; off > 0; off >>= 1)
        s += __shfl_down(s, off, 64);
    if (lane == 0)
        out[VQ_OUTQ] = (float)(1.25 * s / 8388608.0);
}

extern "C" void kernel_launch(void* const* d_in, const int* in_sizes, int n_in,
                              void* d_out, int out_size, void* d_ws, size_t ws_size,
                              hipStream_t stream)
{
    const float* x   = (const float*)d_in[0];
    const float* emb = (const float*)d_in[1];
    float* out = (float*)d_out;

    short8* frag = (short8*)d_ws;                          // 65536 B
    float*  ctab = (float*)((char*)d_ws + 65536);          // 2048 B
    double* buck = (double*)((char*)d_ws + 65536 + 2048);  // 2048 B

    vq_prep<<<dim3(16), dim3(256), 0, stream>>>(emb, frag, ctab, buck);
    vq_main<<<dim3(512), dim3(512), 0, stream>>>(x, emb, frag, ctab, out, buck);
    vq_finalize<<<dim3(1), dim3(64), 0, stream>>>(buck, out);
}